// Round 6
// baseline (123.951 us; speedup 1.0000x reference)
//
#include <hip/hip_runtime.h>

#define BB   8
#define SS   4096
#define DD   64
#define NBB  32

typedef float f32x4 __attribute__((ext_vector_type(4)));
typedef short s16x8 __attribute__((ext_vector_type(8)));

#if defined(__has_builtin)
#if __has_builtin(__builtin_amdgcn_exp2f)
#define EXP2(x) __builtin_amdgcn_exp2f(x)
#else
#define EXP2(x) exp2f(x)
#endif
#else
#define EXP2(x) exp2f(x)
#endif

#define MFMA16(a, b, c) __builtin_amdgcn_mfma_f32_16x16x32_bf16((a), (b), (c), 0, 0, 0)

__device__ __forceinline__ unsigned short f2bf(float x) {
  unsigned u = __builtin_bit_cast(unsigned, x);
  u += 0x7fffu + ((u >> 16) & 1u);
  return (unsigned short)(u >> 16);
}

// packed f32x2 -> bf16x2 (RNE), single instruction
__device__ __forceinline__ unsigned cvtpk(float lo, float hi) {
  unsigned r;
  asm("v_cvt_pk_bf16_f32 %0, %1, %2" : "=v"(r) : "v"(lo), "v"(hi));
  return r;
}

__device__ __forceinline__ void gl_lds16(const void* g, void* l) {
  __builtin_amdgcn_global_load_lds(
      (const __attribute__((address_space(1))) unsigned int*)g,
      (__attribute__((address_space(3))) unsigned int*)l, 16, 0, 0);
}

// ---------------- prep (512 thr) ----------------
// K image (16KB/blk): byte[row*128 + ((2d) ^ ((row&7)<<4))] = bf16(K[row][d])
// V image (16KB/blk): kv = s*32+h*16+g*4+t -> byte[d*256 + ((s*64+g*16+h*8+2t) ^ ((d&7)<<4))]
//   (h-permuted columns so the QK^T accumulator IS the PV B-fragment)
__global__ __launch_bounds__(512) void bsattn_prep(
    const float* __restrict__ kp, const float* __restrict__ vp,
    char* __restrict__ kimg, char* __restrict__ vimg) {
  __shared__ float vt[128 * 68];  // fp32 V tile (row kv, col d), padded
  const int tid = threadIdx.x;
  const int blk = blockIdx.x;  // b*NBB + kb
  const float* kbp = kp + (size_t)blk * 128 * DD;
  const float* vbp = vp + (size_t)blk * 128 * DD;
  char* kdst = kimg + ((size_t)blk << 14);
  char* vdst = vimg + ((size_t)blk << 14);
  const int drow = tid & 15, rr = tid >> 4;  // rr 0..31
#pragma unroll
  for (int p = 0; p < 4; ++p) {
    int row = p * 32 + rr;
    float4 kx = *(const float4*)(kbp + row * DD + drow * 4);
    ushort4 k4;
    k4.x = f2bf(kx.x); k4.y = f2bf(kx.y); k4.z = f2bf(kx.z); k4.w = f2bf(kx.w);
    *(ushort4*)(kdst + row * 128 + ((drow * 8) ^ ((row & 7) << 4))) = k4;
    float4 vx = *(const float4*)(vbp + row * DD + drow * 4);
    *(float4*)(&vt[row * 68 + drow * 4]) = vx;
  }
  __syncthreads();
  const int l5 = tid & 31, dtop = tid >> 5;  // dtop 0..15
  const int kv0 = l5 * 4;  // s=l5>>3, h=(l5>>2)&1, g=l5&3
  const int c0b = ((l5 >> 3) * 64) + ((l5 & 3) * 16) + (((l5 >> 2) & 1) * 8);
#pragma unroll
  for (int p = 0; p < 4; ++p) {
    int d = p * 16 + dtop;
    ushort4 v4;
    v4.x = f2bf(vt[(kv0 + 0) * 68 + d]);
    v4.y = f2bf(vt[(kv0 + 1) * 68 + d]);
    v4.z = f2bf(vt[(kv0 + 2) * 68 + d]);
    v4.w = f2bf(vt[(kv0 + 3) * 68 + d]);
    *(ushort4*)(vdst + d * 256 + (c0b ^ ((d & 7) << 4))) = v4;
  }
}

// ---------------- main ----------------
// Grid 1024 = (b:8) x (qb:32) x (qt:4).  WG = 32 q rows, 8 waves = wq:2 x wk:4
// (16 q x 32 kv per wave per block).  Single 32KB K+V buffer -> 4 WG/CU =
// 32 waves/CU (full).  Swapped MFMA; in-register softmax (8 els/lane, deferred
// cross-lane sum); PV B-frag = cvt_pk'd QK accumulator via V-image k-permutation.
__global__ __launch_bounds__(512, 8) void bsattn_main(
    const float* __restrict__ qp, const int* __restrict__ layout,
    const char* __restrict__ kimg, const char* __restrict__ vimg,
    float* __restrict__ out) {
  __shared__ alignas(16) char smem[32768];  // K at 0 (16KB), V^T at 16384 (16KB)

  const int tid = threadIdx.x, lane = tid & 63, wid = tid >> 6;
  const int wq = wid >> 2, wk = wid & 3;
  const int l16 = lane & 15, lg = lane >> 4;
  const int l7 = l16 & 7;

  const int bidx = blockIdx.x;
  const int b = bidx & 7;       // one batch per XCD
  const int idx = bidx >> 3;    // 0..127
  const int qb = idx >> 2, qt = idx & 3;
  const int qrow_g = qb * 128 + qt * 32 + wq * 16 + l16;  // this lane's q row

  // live-block bitmask (wave-uniform scalar)
  unsigned long long mask =
      __ballot((lane < 32) && (layout[qb * NBB + lane] != 0));
  const int nlive = __popcll(mask);
  unsigned long long rem = mask;

  // Q fragment (B-operand: col q=l16, k=d), pre-scaled by log2(e)/sqrt(D)
  const float qscale = 0.18033688011112042f;
  s16x8 qf[2];
  {
    const float* qrow = qp + ((size_t)b * SS + qrow_g) * DD;
#pragma unroll
    for (int kc = 0; kc < 2; ++kc) {
      const float* p0 = qrow + kc * 32 + lg * 8;
      float4 x = *(const float4*)(p0);
      float4 y = *(const float4*)(p0 + 4);
      s16x8 f;
      f[0] = (short)f2bf(x.x * qscale); f[1] = (short)f2bf(x.y * qscale);
      f[2] = (short)f2bf(x.z * qscale); f[3] = (short)f2bf(x.w * qscale);
      f[4] = (short)f2bf(y.x * qscale); f[5] = (short)f2bf(y.y * qscale);
      f[6] = (short)f2bf(y.z * qscale); f[7] = (short)f2bf(y.w * qscale);
      qf[kc] = f;
    }
  }

  f32x4 o_acc[4];
  float mreg = -INFINITY, psum = 0.0f;
#pragma unroll
  for (int dch = 0; dch < 4; ++dch) o_acc[dch] = (f32x4)(0.0f);

  const size_t imgbase = ((size_t)(b * NBB) << 14);
  const int st_g = wid * 2048 + lane * 16;  // global src offset (per-lane)
  const int st_l = wid * 2048;              // LDS dst offset (wave-uniform)

#define STAGE(kbv)                                                      \
  do {                                                                  \
    const char* ks_ = kimg + imgbase + ((size_t)(kbv) << 14) + st_g;    \
    const char* vs_ = vimg + imgbase + ((size_t)(kbv) << 14) + st_g;    \
    _Pragma("unroll")                                                   \
    for (int i_ = 0; i_ < 2; ++i_) {                                    \
      gl_lds16(ks_ + i_ * 1024, smem + st_l + i_ * 1024);               \
      gl_lds16(vs_ + i_ * 1024, smem + 16384 + st_l + i_ * 1024);       \
    }                                                                   \
  } while (0)

  // prologue: stage first live block
  {
    int kb0 = (int)__builtin_ctzll(rem);
    rem &= rem - 1;
    STAGE(kb0);
  }
  __syncthreads();  // includes per-wave vmcnt drain

  for (int i = 0; i < nlive; ++i) {
    // ---- QK^T (S^T: rows kv-quarter, cols q=l16) ----
    f32x4 sc[2];
    sc[0] = (f32x4)(0.0f);
    sc[1] = (f32x4)(0.0f);
    __builtin_amdgcn_s_setprio(1);
#pragma unroll
    for (int kvc = 0; kvc < 2; ++kvc) {
      const char* kr = smem + (wk * 32 + kvc * 16 + l16) * 128;
#pragma unroll
      for (int kc = 0; kc < 2; ++kc) {
        s16x8 ak = *(const s16x8*)(kr + (((kc * 4 + lg) ^ l7) << 4));
        sc[kvc] = MFMA16(ak, qf[kc], sc[kvc]);
      }
    }
    __builtin_amdgcn_s_setprio(0);

    // ---- online softmax: 8 local kv; lane-consistent max; deferred sum ----
    float mx = fmaxf(fmaxf(fmaxf(sc[0][0], sc[0][1]), fmaxf(sc[0][2], sc[0][3])),
                     fmaxf(fmaxf(sc[1][0], sc[1][1]), fmaxf(sc[1][2], sc[1][3])));
    mx = fmaxf(mx, __shfl_xor(mx, 16));
    mx = fmaxf(mx, __shfl_xor(mx, 32));
    // defer-max (T13): only rescale when the running max grew by > 5 (log2)
    if (!__all(mx - mreg <= 5.0f)) {
      float mn = fmaxf(mreg, mx);
      float al = EXP2(mreg - mn);
      mreg = mn;
      psum *= al;
#pragma unroll
      for (int dch = 0; dch < 4; ++dch) o_acc[dch] *= al;
    }
    {
      const float mn = mreg;
#pragma unroll
      for (int kvc = 0; kvc < 2; ++kvc)
#pragma unroll
        for (int r = 0; r < 4; ++r) {
          float e = EXP2(sc[kvc][r] - mn);
          sc[kvc][r] = e;
          psum += e;
        }
    }
    // pack P^T fragment: u16[h*4+t] = P[kv = wk*32 + h*16 + lg*4 + t]
    s16x8 pf;
    {
      int4 pk;
      pk.x = (int)cvtpk(sc[0][0], sc[0][1]);
      pk.y = (int)cvtpk(sc[0][2], sc[0][3]);
      pk.z = (int)cvtpk(sc[1][0], sc[1][1]);
      pk.w = (int)cvtpk(sc[1][2], sc[1][3]);
      pf = __builtin_bit_cast(s16x8, pk);
    }

    // ---- PV (O^T += V^T * P^T), k-mapping matches the permuted V image ----
    __builtin_amdgcn_s_setprio(1);
    const int colb = (((wk * 4 + lg) ^ l7) << 4);
#pragma unroll
    for (int dch = 0; dch < 4; ++dch) {
      s16x8 av = *(const s16x8*)(smem + 16384 + (dch * 16 + l16) * 256 + colb);
      o_acc[dch] = MFMA16(av, pf, o_acc[dch]);
    }
    __builtin_amdgcn_s_setprio(0);

    __syncthreads();  // all waves done reading the buffer
    if (i + 1 < nlive) {
      int kbn = (int)__builtin_ctzll(rem);
      rem &= rem - 1;
      STAGE(kbn);
    }
    __syncthreads();  // stage landed (per-wave vmcnt drain) + visible to all
  }

  // finalize deferred sum: reduce psum across lg groups
  float lreg = psum;
  lreg += __shfl_xor(lreg, 16);
  lreg += __shfl_xor(lreg, 32);

  // ---- merge 4 kv quarters: wk=1..3 publish, wk=0 merges + stores ----
  float* Opub = (float*)smem;          // 3 x [32 q][64 d] fp32 = 24KB
  float* Ml = (float*)(smem + 24576);  // m[3][32], l[3][32]
  const int qlW = wq * 16 + l16;       // 0..31
  if (wk != 0) {
    float* orow = Opub + ((wk - 1) * 32 + qlW) * 64;
#pragma unroll
    for (int dch = 0; dch < 4; ++dch)
      *(f32x4*)(&orow[dch * 16 + lg * 4]) = o_acc[dch];
    if (lg == 0) {
      Ml[(wk - 1) * 32 + qlW] = mreg;
      Ml[96 + (wk - 1) * 32 + qlW] = lreg;
    }
  }
  __syncthreads();
  if (wk == 0) {
    float m1 = Ml[qlW], m2 = Ml[32 + qlW], m3 = Ml[64 + qlW];
    float l1 = Ml[96 + qlW], l2 = Ml[128 + qlW], l3 = Ml[160 + qlW];
    float mm = fmaxf(fmaxf(mreg, m1), fmaxf(m2, m3));
    float a0 = EXP2(mreg - mm), a1 = EXP2(m1 - mm);
    float a2 = EXP2(m2 - mm), a3 = EXP2(m3 - mm);
    float inv = 1.0f / (lreg * a0 + l1 * a1 + l2 * a2 + l3 * a3);
    float* gout = out + ((size_t)b * SS + qrow_g) * DD;
#pragma unroll
    for (int dch = 0; dch < 4; ++dch) {
      const int co = dch * 16 + lg * 4;
      f32x4 o1 = *(const f32x4*)(&Opub[(0 * 32 + qlW) * 64 + co]);
      f32x4 o2 = *(const f32x4*)(&Opub[(1 * 32 + qlW) * 64 + co]);
      f32x4 o3 = *(const f32x4*)(&Opub[(2 * 32 + qlW) * 64 + co]);
      f32x4 r = (o_acc[dch] * a0 + o1 * a1 + o2 * a2 + o3 * a3) * inv;
      *(f32x4*)(gout + co) = r;
    }
  }
#undef STAGE
}

extern "C" void kernel_launch(void* const* d_in, const int* in_sizes, int n_in,
                              void* d_out, int out_size, void* d_ws, size_t ws_size,
                              hipStream_t stream) {
  (void)in_sizes; (void)n_in; (void)out_size; (void)ws_size;
  const float* q = (const float*)d_in[0];
  const float* k = (const float*)d_in[1];
  const float* v = (const float*)d_in[2];
  const int* layout = (const int*)d_in[3];
  float* out = (float*)d_out;
  char* kimg = (char*)d_ws;               // 4 MB
  char* vimg = (char*)d_ws + (4u << 20);  // 4 MB
  bsattn_prep<<<dim3(BB * NBB), dim3(512), 0, stream>>>(k, v, kimg, vimg);
  bsattn_main<<<dim3(1024), dim3(512), 0, stream>>>(q, layout, kimg, vimg, out);
}